// Round 12
// baseline (7184.042 us; speedup 1.0000x reference)
//
#include <hip/hip_runtime.h>
#include <math.h>

#define TSTEPS 512
#define B      64
#define I      512
#define H      512
#define G      2048   // 4*H
#define K      1024   // I + H

typedef __attribute__((ext_vector_type(8))) short          short8;  // MFMA frag
typedef __attribute__((ext_vector_type(8))) unsigned short u16x8;
typedef __attribute__((ext_vector_type(4))) float          f32x4;
typedef unsigned long long ull;

__device__ __forceinline__ unsigned short f2bf(float f) {
    union { float f; unsigned int u; } v; v.f = f;
    unsigned int r = v.u + 0x7fffu + ((v.u >> 16) & 1u);   // RNE
    return (unsigned short)(r >> 16);
}
__device__ __forceinline__ float bf2f(unsigned short b) {
    union { unsigned int u; float f; } v; v.u = ((unsigned int)b) << 16;
    return v.f;
}

// persist packing (R6-proven): col = cg*32 + hj*4 + gate  (gate fastest)
//   <-> g = gate*H + cg*8 + hj    (cg = col>>5, in [0,64))
__device__ __forceinline__ int col2g3(int col) {
    int w = col & 31, cg = col >> 5;
    return (w & 3) * H + cg * 8 + (w >> 2);
}
// fallback packing (round-2 proven)
__device__ __forceinline__ int col2g_fb(int col) {
    int w = col & 31, nb = col >> 5;
    return (w >> 3) * H + nb * 8 + (w & 7);
}

// ===========================================================================
// PERSISTENT PATH
// ===========================================================================

__global__ void conv_x(const float* __restrict__ in, unsigned short* __restrict__ xbf) {
    int i = blockIdx.x * 256 + threadIdx.x;
    size_t base = (size_t)i * 8;
    float4 a = *(const float4*)(in + base);
    float4 b = *(const float4*)(in + base + 4);
    u16x8 o;
    o[0]=f2bf(a.x); o[1]=f2bf(a.y); o[2]=f2bf(a.z); o[3]=f2bf(a.w);
    o[4]=f2bf(b.x); o[5]=f2bf(b.y); o[6]=f2bf(b.z); o[7]=f2bf(b.w);
    *(u16x8*)(xbf + base) = o;
}

__global__ void pack_w2(const float* __restrict__ wih,
                        const float* __restrict__ whh,
                        unsigned short* __restrict__ wihP,
                        unsigned short* __restrict__ whhP) {
    int idx = blockIdx.x * 256 + threadIdx.x;   // [0, G*128)
    int col = idx >> 7;
    int k0  = (idx & 127) << 2;
    int g = col2g3(col);
    float4 a = *(const float4*)(wih + (size_t)g * I + k0);
    float4 b = *(const float4*)(whh + (size_t)g * H + k0);
    ushort4 oa = { f2bf(a.x), f2bf(a.y), f2bf(a.z), f2bf(a.w) };
    ushort4 ob = { f2bf(b.x), f2bf(b.y), f2bf(b.z), f2bf(b.w) };
    *(ushort4*)(wihP + (size_t)col * I + k0) = oa;
    *(ushort4*)(whhP + (size_t)col * H + k0) = ob;
}

// tagged h(0): hb0u[i] = (tag=1)<<16 | bf16(hx[i])
__global__ void init_state_p(const float* __restrict__ hx,
                             const float* __restrict__ bih,
                             const float* __restrict__ bhh,
                             unsigned int* __restrict__ hb0u,
                             float* __restrict__ bias2) {
    int i = blockIdx.x * 256 + threadIdx.x;
    if (i < B * H) hb0u[i] = (1u << 16) | (unsigned int)f2bf(hx[i]);
    if (i < G) bias2[i] = bih[col2g3(i)] + bhh[col2g3(i)];
}

// xp[cg][t][b][32] bf16.  grid (512 t, 16 ncb), 256 thr.  (R6-proven)
#define LDA 136
#define LDB 136
__global__ __launch_bounds__(256) void xproj_gemm(
    const unsigned short* __restrict__ xbf,   // [T*B][I]
    const unsigned short* __restrict__ wihP,  // [G][I] packed col2g3
    unsigned short* __restrict__ xp)          // [64][512][64][32]
{
    __shared__ unsigned short atile[64 * LDA];
    __shared__ unsigned short btile[128 * LDB];

    const int t   = blockIdx.x;
    const int ncb = blockIdx.y;
    const int tid  = threadIdx.x;
    const int lane = tid & 63;
    const int wv   = tid >> 6;
    const int fr   = lane & 15;
    const int fk   = (lane >> 4) * 8;
    const int mt   = wv & 1;
    const int nt   = wv >> 1;

    f32x4 acc[2][4];
    #pragma unroll
    for (int mi = 0; mi < 2; ++mi)
        #pragma unroll
        for (int ni = 0; ni < 4; ++ni) acc[mi][ni] = (f32x4){0.f,0.f,0.f,0.f};

    const int arow = tid >> 2, aseg = tid & 3;
    const int brow = tid >> 1, bseg = tid & 1;

    for (int kt = 0; kt < I; kt += 128) {
        {
            const u16x8* src = (const u16x8*)(xbf + ((size_t)t * 64 + arow) * I + kt);
            #pragma unroll
            for (int j = 0; j < 4; ++j) {
                int ch = aseg + 4 * j;
                *(u16x8*)(atile + arow * LDA + ch * 8) = src[ch];
            }
        }
        {
            const u16x8* src = (const u16x8*)(wihP + ((size_t)ncb * 128 + brow) * I + kt);
            #pragma unroll
            for (int j = 0; j < 8; ++j) {
                int ch = bseg + 2 * j;
                *(u16x8*)(btile + brow * LDB + ch * 8) = src[ch];
            }
        }
        __syncthreads();
        #pragma unroll
        for (int ks = 0; ks < 4; ++ks) {
            short8 af[2], bf[4];
            #pragma unroll
            for (int mi = 0; mi < 2; ++mi)
                af[mi] = *(const short8*)(atile + (mt*32 + mi*16 + fr) * LDA + fk + ks*32);
            #pragma unroll
            for (int ni = 0; ni < 4; ++ni)
                bf[ni] = *(const short8*)(btile + (nt*64 + ni*16 + fr) * LDB + fk + ks*32);
            #pragma unroll
            for (int mi = 0; mi < 2; ++mi)
                #pragma unroll
                for (int ni = 0; ni < 4; ++ni)
                    acc[mi][ni] = __builtin_amdgcn_mfma_f32_16x16x32_bf16(af[mi], bf[ni], acc[mi][ni], 0, 0, 0);
        }
        __syncthreads();
    }

    #pragma unroll
    for (int mi = 0; mi < 2; ++mi)
        #pragma unroll
        for (int ni = 0; ni < 4; ++ni)
            #pragma unroll
            for (int e = 0; e < 4; ++e) {
                int row = mt*32 + mi*16 + (lane >> 4) * 4 + e;       // batch b
                int c   = ncb*128 + nt*64 + ni*16 + fr;              // packed col
                int cgv = c >> 5, coff = c & 31;
                xp[(((size_t)cgv * TSTEPS + t) * 64 + row) * 32 + coff] = f2bf(acc[mi][ni][e]);
            }
}

// ---------------------------------------------------------------------------
// Persistent LSTM (R6 geometry, 2-hop protocol): grid (64 cg, 4 bg), 256 thr.
// h exchange: TAGGED u32 words ((t+2)<<16 | bf16), direct pair-packed u64 sc1
// stores from cell registers; flag stored immediately (NO vmcnt drain) —
// consumers poll flags (all 4 waves independently, no extra barrier), then
// verify tags on pre-issued speculative loads, retrying rare stragglers.
// 2 barriers/step. Both tagged buffers + flags memset per launch (replay-safe).
// ---------------------------------------------------------------------------
#define LDH2 520
#define LDW2 520
__global__ __launch_bounds__(256) void lstm_persist_tf(
    const unsigned short* __restrict__ xp,     // [64][512][64][32]
    const unsigned short* __restrict__ whhP,   // [G][H] packed col2g3
    const float* __restrict__ bias2,           // [G] packed
    const float* __restrict__ cx,              // [B][H]
    unsigned int* __restrict__ hb0u,           // [B][H] tagged u32 (tag1 = hx)
    unsigned int* __restrict__ hb1u,           // [B][H] tagged u32 (zeroed)
    float* __restrict__ out,                   // [2][B][H]
    unsigned int* __restrict__ flags)          // [4][64] u32 @128B spacing, 0
{
    __shared__ unsigned short hsm[16 * LDH2];   // 16.6 KB
    __shared__ unsigned short wsm[32 * LDW2];   // 33.3 KB
    __shared__ float gbufs[2][16][36];          //  4.6 KB

    const int tid  = threadIdx.x;
    const int cg   = blockIdx.x;               // [0,64)
    const int bg   = blockIdx.y;               // [0,4)
    const int lane = tid & 63;
    const int wv   = tid >> 6;                 // [0,4)
    const int fr   = lane & 15;
    const int fk   = (lane >> 4) * 8;
    const int nt   = wv & 1;                   // N-tile (16 cols)
    const int kh   = wv >> 1;                  // K-half

    // ---- stage whh slice once: 32 packed cols x 512 k ----
    {
        int row = tid >> 3, seg = tid & 7;
        const u16x8* src = (const u16x8*)(whhP + ((size_t)cg * 32 + row) * H + seg * 64);
        unsigned short* dst = wsm + row * LDW2 + seg * 64;
        #pragma unroll
        for (int q = 0; q < 8; ++q) *(u16x8*)(dst + q * 8) = src[q];
    }

    // ---- per-thread cell state (threads 0..127) ----
    const int bl   = tid >> 3;                 // local batch row (valid tid<128)
    const int hj   = tid & 7;
    const int hcol = cg * 8 + hj;
    const int bglob = bg * 16 + (bl & 15);
    float creg = 0.f;
    float4 bias4 = {0.f, 0.f, 0.f, 0.f};
    if (tid < 128) {
        creg  = cx[(size_t)bglob * H + hcol];
        bias4 = *(const float4*)&bias2[cg * 32 + hj * 4];  // i,f,g,o
    }

    // h poll/stage map: 16 thr/row, 32 tagged u32 (16 u64) per thread
    const int srow = tid >> 4, sseg = tid & 15;

    const unsigned short* xpb =
        xp + (((size_t)cg * TSTEPS) * 64 + bg * 16 + (bl & 15)) * 32 + hj * 4;
    ushort4 xv = {0, 0, 0, 0};
    if (tid < 128) xv = *(const ushort4*)xpb;

    const unsigned int* gflags = flags + (size_t)bg * 64 * 32;
    float hout = 0.f;

    for (int t = 0; t < TSTEPS; ++t) {
        const unsigned int* hpu = (t & 1) ? hb1u : hb0u;   // state t
        unsigned int*       hnu = (t & 1) ? hb0u : hb1u;   // state t+1
        const unsigned int tg = (unsigned int)(t + 1);     // tag of state t

        // ---- 1. speculative tagged loads (fly during the poll) ----
        const ull* gp = (const ull*)(hpu + ((size_t)bg * 16 + srow) * H + sseg * 32);
        ull v[16];
        #pragma unroll
        for (int q = 0; q < 16; ++q)
            v[q] = __hip_atomic_load(gp + q, __ATOMIC_RELAXED,
                                     __HIP_MEMORY_SCOPE_AGENT);

        // xp prefetch for t+1 (plain cached)
        ushort4 xnext = xv;
        if (tid < 128 && t + 1 < TSTEPS)
            xnext = *(const ushort4*)(xpb + (size_t)(t + 1) * 64 * 32);

        // ---- 2. poll flags >= t (all 4 waves independently; no barrier) ----
        if (t > 0) {
            const unsigned int* fp = gflags + lane * 32;
            const unsigned int tgt = (unsigned int)t;
            unsigned int val;
            do {
                val = __hip_atomic_load(fp, __ATOMIC_RELAXED,
                                        __HIP_MEMORY_SCOPE_AGENT);
            } while (__ballot(val < tgt));
        }

        // ---- 3. verify tags; retry stragglers (rare post-poll) ----
        while (true) {
            bool ok = true;
            #pragma unroll
            for (int q = 0; q < 16; ++q) {
                ok = ok && ((((unsigned int)v[q] >> 16) & 0xffffu) == tg);
                ok = ok && (((unsigned int)(v[q] >> 48)) == tg);
            }
            if (ok) break;
            #pragma unroll
            for (int q = 0; q < 16; ++q)
                v[q] = __hip_atomic_load(gp + q, __ATOMIC_RELAXED,
                                         __HIP_MEMORY_SCOPE_AGENT);
        }

        // ---- 4. strip tags, pack bf16 pairs -> LDS ----
        {
            unsigned int* dst = (unsigned int*)(hsm + srow * LDH2 + sseg * 32);
            #pragma unroll
            for (int q = 0; q < 16; ++q)
                dst[q] = ((unsigned int)v[q] & 0xffffu) |
                         (((unsigned int)(v[q] >> 32) & 0xffffu) << 16);
        }
        __syncthreads();   // S1: h staged

        // ---- 5. wave (nt,kh): 8 MFMAs over its K-half ----
        {
            f32x4 accA = {0.f,0.f,0.f,0.f}, accB = {0.f,0.f,0.f,0.f};
            const unsigned short* ap = hsm + fr * LDH2 + kh * 256 + fk;
            const unsigned short* bp = wsm + (nt * 16 + fr) * LDW2 + kh * 256 + fk;
            #pragma unroll
            for (int ks = 0; ks < 8; ks += 2) {
                short8 a0 = *(const short8*)(ap + ks * 32);
                short8 b0 = *(const short8*)(bp + ks * 32);
                accA = __builtin_amdgcn_mfma_f32_16x16x32_bf16(a0, b0, accA, 0, 0, 0);
                short8 a1 = *(const short8*)(ap + ks * 32 + 32);
                short8 b1 = *(const short8*)(bp + ks * 32 + 32);
                accB = __builtin_amdgcn_mfma_f32_16x16x32_bf16(a1, b1, accB, 0, 0, 0);
            }
            #pragma unroll
            for (int e = 0; e < 4; ++e)
                gbufs[kh][(lane >> 4) * 4 + e][nt * 16 + fr] = accA[e] + accB[e];
        }
        __syncthreads();   // S2: gates complete

        // ---- 6. cell update + tagged publish + flag (no drain) ----
        if (tid < 128) {
            float4 g0 = *(const float4*)&gbufs[0][bl & 15][hj * 4];
            float4 g1 = *(const float4*)&gbufs[1][bl & 15][hj * 4];
            float ig = g0.x + g1.x + bf2f(xv.x) + bias4.x;
            float fg = g0.y + g1.y + bf2f(xv.y) + bias4.y;
            float gg = g0.z + g1.z + bf2f(xv.z) + bias4.z;
            float og = g0.w + g1.w + bf2f(xv.w) + bias4.w;
            ig = 1.f / (1.f + __expf(-ig));
            fg = 1.f / (1.f + __expf(-fg));
            og = 1.f / (1.f + __expf(-og));
            gg = tanhf(gg);
            creg = fg * creg + ig * gg;
            hout = og * tanhf(creg);

            if (t < TSTEPS - 1) {
                unsigned int word = ((unsigned int)(t + 2) << 16) | (unsigned int)f2bf(hout);
                unsigned int other = (unsigned int)__shfl_xor((int)word, 1, 64);
                if (!(hj & 1)) {
                    ull pair = (ull)word | ((ull)other << 32);
                    ull* dst = (ull*)(hnu + (size_t)bglob * H + hcol);
                    __hip_atomic_store(dst, pair, __ATOMIC_RELAXED,
                                       __HIP_MEMORY_SCOPE_AGENT);
                }
            }
        }
        if (tid == 0 && t < TSTEPS - 1)
            __hip_atomic_store((unsigned int*)(gflags + cg * 32), (unsigned int)(t + 1),
                               __ATOMIC_RELAXED, __HIP_MEMORY_SCOPE_AGENT);
        xv = xnext;
    }

    if (tid < 128) {
        out[(size_t)bglob * H + hcol] = hout;                       // hy
        out[(size_t)B * H + (size_t)bglob * H + hcol] = creg;       // cy
    }
}

// ===========================================================================
// FALLBACK PATH (round-2 proven): per-step launches, K=1024
// ===========================================================================
#define KT  256
#define LDP 264

__global__ void init_state_fb(const float* __restrict__ hx,
                              const float* __restrict__ cx,
                              const float* __restrict__ bih,
                              const float* __restrict__ bhh,
                              unsigned short* __restrict__ hbf0,
                              float* __restrict__ cbuf,
                              float* __restrict__ bias2) {
    int i = blockIdx.x * 256 + threadIdx.x;
    if (i < B * H) { hbf0[i] = f2bf(hx[i]); cbuf[i] = cx[i]; }
    if (i < G) bias2[i] = bih[col2g_fb(i)] + bhh[col2g_fb(i)];
}

__global__ void pack_w(const float* __restrict__ wih,
                       const float* __restrict__ whh,
                       unsigned short* __restrict__ wbf) {
    int idx = blockIdx.x * 256 + threadIdx.x;
    int col = idx >> 8;
    int k0  = (idx & 255) << 2;
    int g = col2g_fb(col);
    float4 v = (k0 < I) ? *(const float4*)(wih + (size_t)g * I + k0)
                        : *(const float4*)(whh + (size_t)g * H + (k0 - I));
    ushort4 o = { f2bf(v.x), f2bf(v.y), f2bf(v.z), f2bf(v.w) };
    *(ushort4*)(wbf + (size_t)col * K + k0) = o;
}

__global__ __launch_bounds__(256) void lstm_step(
    const float* __restrict__ x_t,
    const unsigned short* __restrict__ wbf,
    const float* __restrict__ bias2,
    const unsigned short* __restrict__ h_prev,
    unsigned short* __restrict__ h_next,
    float* __restrict__ c)
{
    __shared__ unsigned short xs [32 * LDP];
    __shared__ unsigned short wsm2[32 * LDP];
    __shared__ float gbuf[32][33];

    const int tid  = threadIdx.x;
    const int mg   = blockIdx.x;
    const int nb   = blockIdx.y;
    const int lane = tid & 63;
    const int wv   = tid >> 6;
    const int rbase = mg * 32;
    const int cbase = nb * 32;
    const int fr = lane & 15;
    const int fk = (lane >> 4) * 8;
    const int sr = tid >> 3;
    const int sc = (tid & 7) * 8;

    f32x4 accA = {0.f,0.f,0.f,0.f}, accB = {0.f,0.f,0.f,0.f};

    for (int kt = 0; kt < K; kt += KT) {
        if (kt < I) {
            const float* src = x_t + (size_t)(rbase + sr) * I + kt;
            unsigned short* dst = xs + sr * LDP;
            #pragma unroll
            for (int j = 0; j < 4; ++j) {
                int k = sc + j * 64;
                float4 a = *(const float4*)(src + k);
                float4 b = *(const float4*)(src + k + 4);
                u16x8 o;
                o[0]=f2bf(a.x); o[1]=f2bf(a.y); o[2]=f2bf(a.z); o[3]=f2bf(a.w);
                o[4]=f2bf(b.x); o[5]=f2bf(b.y); o[6]=f2bf(b.z); o[7]=f2bf(b.w);
                *(u16x8*)(dst + k) = o;
            }
        } else {
            const unsigned short* src = h_prev + (size_t)(rbase + sr) * H + (kt - I);
            unsigned short* dst = xs + sr * LDP;
            #pragma unroll
            for (int j = 0; j < 4; ++j) {
                int k = sc + j * 64;
                *(u16x8*)(dst + k) = *(const u16x8*)(src + k);
            }
        }
        {
            const unsigned short* src = wbf + (size_t)(cbase + sr) * K + kt;
            unsigned short* dst = wsm2 + sr * LDP;
            #pragma unroll
            for (int j = 0; j < 4; ++j) {
                int k = sc + j * 64;
                *(u16x8*)(dst + k) = *(const u16x8*)(src + k);
            }
        }
        __syncthreads();
        const unsigned short* ap = xs   + ((wv & 1) * 16 + fr) * LDP + fk;
        const unsigned short* bp = wsm2 + ((wv >> 1) * 16 + fr) * LDP + fk;
        #pragma unroll
        for (int ks = 0; ks < KT / 32; ++ks) {
            short8 af = *(const short8*)(ap + ks * 32);
            short8 bf = *(const short8*)(bp + ks * 32);
            if (ks & 1) accB = __builtin_amdgcn_mfma_f32_16x16x32_bf16(af, bf, accB, 0, 0, 0);
            else        accA = __builtin_amdgcn_mfma_f32_16x16x32_bf16(af, bf, accA, 0, 0, 0);
        }
        __syncthreads();
    }

    #pragma unroll
    for (int e = 0; e < 4; ++e)
        gbuf[(wv & 1) * 16 + (lane >> 4) * 4 + e][(wv >> 1) * 16 + fr] = accA[e] + accB[e];
    __syncthreads();

    {
        int br = tid >> 3;
        int hj = tid & 7;
        float ig = gbuf[br][ 0 + hj] + bias2[cbase +  0 + hj];
        float fg = gbuf[br][ 8 + hj] + bias2[cbase +  8 + hj];
        float gg = gbuf[br][16 + hj] + bias2[cbase + 16 + hj];
        float og = gbuf[br][24 + hj] + bias2[cbase + 24 + hj];
        ig = 1.f / (1.f + __expf(-ig));
        fg = 1.f / (1.f + __expf(-fg));
        og = 1.f / (1.f + __expf(-og));
        gg = tanhf(gg);
        size_t ci = (size_t)(rbase + br) * H + nb * 8 + hj;
        float cn = fg * c[ci] + ig * gg;
        c[ci] = cn;
        h_next[ci] = f2bf(og * tanhf(cn));
    }
}

__global__ void epilogue(const unsigned short* __restrict__ hbf,
                         const float* __restrict__ cfin,
                         float* __restrict__ out) {
    int i = blockIdx.x * 256 + threadIdx.x;
    if (i < B * H) {
        out[i] = bf2f(hbf[i]);
        out[B * H + i] = cfin[i];
    }
}

// ===========================================================================
extern "C" void kernel_launch(void* const* d_in, const int* in_sizes, int n_in,
                              void* d_out, int out_size, void* d_ws, size_t ws_size,
                              hipStream_t stream) {
    const float* input = (const float*)d_in[0];
    const float* hx    = (const float*)d_in[1];
    const float* cx    = (const float*)d_in[2];
    const float* wih   = (const float*)d_in[3];
    const float* whh   = (const float*)d_in[4];
    const float* bih   = (const float*)d_in[5];
    const float* bhh   = (const float*)d_in[6];
    float* out = (float*)d_out;
    char* ws = (char*)d_ws;

    const size_t PERSIST_WS = 172269568ULL;

    if (ws_size >= PERSIST_WS) {
        unsigned short* xpBuf = (unsigned short*)(ws);                 // 128 MB
        unsigned short* xbf   = (unsigned short*)(ws + 134217728);     // 32 MB
        unsigned short* wihP  = (unsigned short*)(ws + 167772160);     // 2 MB
        unsigned short* whhP  = (unsigned short*)(ws + 169869312);     // 2 MB
        float*          bias2 = (float*)         (ws + 171966464);     // 8 KB
        unsigned int*   hb0u  = (unsigned int*)  (ws + 171974656);     // 128 KB
        unsigned int*   hb1u  = (unsigned int*)  (ws + 172105728);     // 128 KB
        unsigned int*   flags = (unsigned int*)  (ws + 172236800);     // 32 KB

        // zero tagged buffers + flags (contiguous): replay-safe
        hipMemsetAsync(hb0u, 0, 262144 + 32768, stream);
        conv_x<<<(TSTEPS * B * I) / (256 * 8), 256, 0, stream>>>(input, xbf);
        pack_w2<<<(G * 128) / 256, 256, 0, stream>>>(wih, whh, wihP, whhP);
        init_state_p<<<B * H / 256, 256, 0, stream>>>(hx, bih, bhh, hb0u, bias2);
        dim3 ggrid(TSTEPS, G / 128);
        xproj_gemm<<<ggrid, 256, 0, stream>>>(xbf, wihP, xpBuf);
        dim3 pgrid(64, 4);
        lstm_persist_tf<<<pgrid, 256, 0, stream>>>(xpBuf, whhP, bias2, cx,
                                                   hb0u, hb1u, out, flags);
    } else {
        unsigned short* wbf   = (unsigned short*)(ws);
        float*          bias2 = (float*)(ws + 4194304);
        float*          cbuf  = (float*)(ws + 4194304 + 8192);
        unsigned short* hbf0  = (unsigned short*)(ws + 4333568);
        unsigned short* hbf1  = (unsigned short*)(ws + 4399104);

        pack_w<<<G * K / 4 / 256, 256, 0, stream>>>(wih, whh, wbf);
        init_state_fb<<<B * H / 256, 256, 0, stream>>>(hx, cx, bih, bhh, hbf0, cbuf, bias2);
        dim3 grid(2, 64);
        for (int t = 0; t < TSTEPS; ++t) {
            lstm_step<<<grid, 256, 0, stream>>>(
                input + (size_t)t * B * I, wbf, bias2,
                (t & 1) ? hbf1 : hbf0,
                (t & 1) ? hbf0 : hbf1,
                cbuf);
        }
        epilogue<<<B * H / 256, 256, 0, stream>>>(hbf0, cbuf, out);
    }
}

// Round 13
// 1795.871 us; speedup vs baseline: 4.0003x; 4.0003x over previous
//
#include <hip/hip_runtime.h>
#include <math.h>

#define TSTEPS 512
#define B      64
#define I      512
#define H      512
#define G      2048   // 4*H
#define K      1024   // I + H

typedef __attribute__((ext_vector_type(8))) short          short8;  // MFMA frag
typedef __attribute__((ext_vector_type(8))) unsigned short u16x8;
typedef __attribute__((ext_vector_type(4))) float          f32x4;
typedef unsigned long long ull;

__device__ __forceinline__ unsigned short f2bf(float f) {
    union { float f; unsigned int u; } v; v.f = f;
    unsigned int r = v.u + 0x7fffu + ((v.u >> 16) & 1u);   // RNE
    return (unsigned short)(r >> 16);
}
__device__ __forceinline__ float bf2f(unsigned short b) {
    union { unsigned int u; float f; } v; v.u = ((unsigned int)b) << 16;
    return v.f;
}

// persist packing (R6-proven): col = cg*32 + hj*4 + gate  (gate fastest)
//   <-> g = gate*H + cg*8 + hj    (cg = col>>5, in [0,64))
__device__ __forceinline__ int col2g3(int col) {
    int w = col & 31, cg = col >> 5;
    return (w & 3) * H + cg * 8 + (w >> 2);
}
// fallback packing (round-2 proven)
__device__ __forceinline__ int col2g_fb(int col) {
    int w = col & 31, nb = col >> 5;
    return (w >> 3) * H + nb * 8 + (w & 7);
}

// ===========================================================================
// PERSISTENT PATH
// ===========================================================================

__global__ void conv_x(const float* __restrict__ in, unsigned short* __restrict__ xbf) {
    int i = blockIdx.x * 256 + threadIdx.x;
    size_t base = (size_t)i * 8;
    float4 a = *(const float4*)(in + base);
    float4 b = *(const float4*)(in + base + 4);
    u16x8 o;
    o[0]=f2bf(a.x); o[1]=f2bf(a.y); o[2]=f2bf(a.z); o[3]=f2bf(a.w);
    o[4]=f2bf(b.x); o[5]=f2bf(b.y); o[6]=f2bf(b.z); o[7]=f2bf(b.w);
    *(u16x8*)(xbf + base) = o;
}

__global__ void pack_w2(const float* __restrict__ wih,
                        const float* __restrict__ whh,
                        unsigned short* __restrict__ wihP,
                        unsigned short* __restrict__ whhP) {
    int idx = blockIdx.x * 256 + threadIdx.x;   // [0, G*128)
    int col = idx >> 7;
    int k0  = (idx & 127) << 2;
    int g = col2g3(col);
    float4 a = *(const float4*)(wih + (size_t)g * I + k0);
    float4 b = *(const float4*)(whh + (size_t)g * H + k0);
    ushort4 oa = { f2bf(a.x), f2bf(a.y), f2bf(a.z), f2bf(a.w) };
    ushort4 ob = { f2bf(b.x), f2bf(b.y), f2bf(b.z), f2bf(b.w) };
    *(ushort4*)(wihP + (size_t)col * I + k0) = oa;
    *(ushort4*)(whhP + (size_t)col * H + k0) = ob;
}

__global__ void init_state_p(const float* __restrict__ hx,
                             const float* __restrict__ bih,
                             const float* __restrict__ bhh,
                             unsigned short* __restrict__ hbf0,
                             float* __restrict__ bias2) {
    int i = blockIdx.x * 256 + threadIdx.x;
    if (i < B * H) hbf0[i] = f2bf(hx[i]);
    if (i < G) bias2[i] = bih[col2g3(i)] + bhh[col2g3(i)];
}

// xp[cg][t][b][32] bf16.  grid (512 t, 16 ncb), 256 thr.  (R6-proven)
#define LDA 136
#define LDB 136
__global__ __launch_bounds__(256) void xproj_gemm(
    const unsigned short* __restrict__ xbf,   // [T*B][I]
    const unsigned short* __restrict__ wihP,  // [G][I] packed col2g3
    unsigned short* __restrict__ xp)          // [64][512][64][32]
{
    __shared__ unsigned short atile[64 * LDA];
    __shared__ unsigned short btile[128 * LDB];

    const int t   = blockIdx.x;
    const int ncb = blockIdx.y;
    const int tid  = threadIdx.x;
    const int lane = tid & 63;
    const int wv   = tid >> 6;
    const int fr   = lane & 15;
    const int fk   = (lane >> 4) * 8;
    const int mt   = wv & 1;
    const int nt   = wv >> 1;

    f32x4 acc[2][4];
    #pragma unroll
    for (int mi = 0; mi < 2; ++mi)
        #pragma unroll
        for (int ni = 0; ni < 4; ++ni) acc[mi][ni] = (f32x4){0.f,0.f,0.f,0.f};

    const int arow = tid >> 2, aseg = tid & 3;
    const int brow = tid >> 1, bseg = tid & 1;

    for (int kt = 0; kt < I; kt += 128) {
        {
            const u16x8* src = (const u16x8*)(xbf + ((size_t)t * 64 + arow) * I + kt);
            #pragma unroll
            for (int j = 0; j < 4; ++j) {
                int ch = aseg + 4 * j;
                *(u16x8*)(atile + arow * LDA + ch * 8) = src[ch];
            }
        }
        {
            const u16x8* src = (const u16x8*)(wihP + ((size_t)ncb * 128 + brow) * I + kt);
            #pragma unroll
            for (int j = 0; j < 8; ++j) {
                int ch = bseg + 2 * j;
                *(u16x8*)(btile + brow * LDB + ch * 8) = src[ch];
            }
        }
        __syncthreads();
        #pragma unroll
        for (int ks = 0; ks < 4; ++ks) {
            short8 af[2], bf[4];
            #pragma unroll
            for (int mi = 0; mi < 2; ++mi)
                af[mi] = *(const short8*)(atile + (mt*32 + mi*16 + fr) * LDA + fk + ks*32);
            #pragma unroll
            for (int ni = 0; ni < 4; ++ni)
                bf[ni] = *(const short8*)(btile + (nt*64 + ni*16 + fr) * LDB + fk + ks*32);
            #pragma unroll
            for (int mi = 0; mi < 2; ++mi)
                #pragma unroll
                for (int ni = 0; ni < 4; ++ni)
                    acc[mi][ni] = __builtin_amdgcn_mfma_f32_16x16x32_bf16(af[mi], bf[ni], acc[mi][ni], 0, 0, 0);
        }
        __syncthreads();
    }

    #pragma unroll
    for (int mi = 0; mi < 2; ++mi)
        #pragma unroll
        for (int ni = 0; ni < 4; ++ni)
            #pragma unroll
            for (int e = 0; e < 4; ++e) {
                int row = mt*32 + mi*16 + (lane >> 4) * 4 + e;       // batch b
                int c   = ncb*128 + nt*64 + ni*16 + fr;              // packed col
                int cgv = c >> 5, coff = c & 31;
                xp[(((size_t)cgv * TSTEPS + t) * 64 + row) * 32 + coff] = f2bf(acc[mi][ni][e]);
            }
}

// ---------------------------------------------------------------------------
// Persistent LSTM v2: R6 protocol byte-for-byte (sc1 loads, vmcnt drain +
// flag store, wv0 64-lane flag poll), with intra-block overhead removed:
// single-stage h (8 u64/thread), split-K waves -> two gbufs, DIRECT
// pair-packed publish from cell registers. 3 barriers + poll-sync per step.
// ---------------------------------------------------------------------------
#define LDH2 520
#define LDW2 520
__global__ __launch_bounds__(256) void lstm_persist_v2(
    const unsigned short* __restrict__ xp,     // [64][512][64][32]
    const unsigned short* __restrict__ whhP,   // [G][H] packed col2g3
    const float* __restrict__ bias2,           // [G] packed
    const float* __restrict__ cx,              // [B][H]
    unsigned short* __restrict__ hb0,          // [B][H] bf16 (h init)
    unsigned short* __restrict__ hb1,
    float* __restrict__ out,                   // [2][B][H]
    unsigned int* __restrict__ flags)          // [4][64] u32 @128B spacing, 0
{
    __shared__ unsigned short hsm[16 * LDH2];   // 16.6 KB
    __shared__ unsigned short wsm[32 * LDW2];   // 33.3 KB
    __shared__ float gbufs[2][16][36];          //  4.6 KB

    const int tid  = threadIdx.x;
    const int cg   = blockIdx.x;               // [0,64)
    const int bg   = blockIdx.y;               // [0,4)
    const int lane = tid & 63;
    const int wv   = tid >> 6;                 // [0,4)
    const int fr   = lane & 15;
    const int fk   = (lane >> 4) * 8;
    const int nt   = wv & 1;                   // N-tile (16 cols)
    const int kh   = wv >> 1;                  // K-half

    // ---- stage whh slice once: 32 packed cols x 512 k ----
    {
        int row = tid >> 3, seg = tid & 7;
        const u16x8* src = (const u16x8*)(whhP + ((size_t)cg * 32 + row) * H + seg * 64);
        unsigned short* dst = wsm + row * LDW2 + seg * 64;
        #pragma unroll
        for (int q = 0; q < 8; ++q) *(u16x8*)(dst + q * 8) = src[q];
    }

    // ---- per-thread cell state (threads 0..127: 16 rows x 8 hj) ----
    const int bl   = tid >> 3;                 // [0,16) for tid<128
    const int hj   = tid & 7;
    const int hcol = cg * 8 + hj;
    const int bglob = bg * 16 + (bl & 15);
    float creg = 0.f;
    float4 bias4 = {0.f, 0.f, 0.f, 0.f};
    if (tid < 128) {
        creg  = cx[(size_t)bglob * H + hcol];
        bias4 = *(const float4*)&bias2[cg * 32 + hj * 4];  // i,f,g,o
    }

    // h staging map: 16 thr/row, 32 shorts (8 u64) per thread
    const int srow = tid >> 4, sseg = tid & 15;

    const unsigned short* xpb =
        xp + (((size_t)cg * TSTEPS) * 64 + bg * 16 + (bl & 15)) * 32 + hj * 4;
    ushort4 xv = {0, 0, 0, 0};
    if (tid < 128) xv = *(const ushort4*)xpb;

    unsigned int* gflags = flags + (size_t)bg * 64 * 32;   // this group's flags
    float hout = 0.f;

    for (int t = 0; t < TSTEPS; ++t) {
        const unsigned short* hp = (t & 1) ? hb1 : hb0;
        unsigned short*       hn = (t & 1) ? hb0 : hb1;

        // xp prefetch for t+1 (independent of sync; flies during the poll)
        ushort4 xnext = xv;
        if (tid < 128 && t + 1 < TSTEPS)
            xnext = *(const ushort4*)(xpb + (size_t)(t + 1) * 64 * 32);

        // ---- wait: all 64 group blocks published h(t) (R6-proven poll) ----
        if (t > 0) {
            if (wv == 0) {
                const unsigned int* fp = gflags + lane * 32;
                const unsigned int tgt = (unsigned int)t;
                unsigned int val;
                do {
                    val = __hip_atomic_load(fp, __ATOMIC_RELAXED,
                                            __HIP_MEMORY_SCOPE_AGENT);
                } while (__ballot(val < tgt));
            }
            __syncthreads();
        }

        // ---- load h (sc1 u64, bypass stale L2): 8 independent loads ----
        {
            const ull* gp = (const ull*)(hp + ((size_t)bg * 16 + srow) * H + sseg * 32);
            ull v0 = __hip_atomic_load(gp+0, __ATOMIC_RELAXED, __HIP_MEMORY_SCOPE_AGENT);
            ull v1 = __hip_atomic_load(gp+1, __ATOMIC_RELAXED, __HIP_MEMORY_SCOPE_AGENT);
            ull v2 = __hip_atomic_load(gp+2, __ATOMIC_RELAXED, __HIP_MEMORY_SCOPE_AGENT);
            ull v3 = __hip_atomic_load(gp+3, __ATOMIC_RELAXED, __HIP_MEMORY_SCOPE_AGENT);
            ull v4 = __hip_atomic_load(gp+4, __ATOMIC_RELAXED, __HIP_MEMORY_SCOPE_AGENT);
            ull v5 = __hip_atomic_load(gp+5, __ATOMIC_RELAXED, __HIP_MEMORY_SCOPE_AGENT);
            ull v6 = __hip_atomic_load(gp+6, __ATOMIC_RELAXED, __HIP_MEMORY_SCOPE_AGENT);
            ull v7 = __hip_atomic_load(gp+7, __ATOMIC_RELAXED, __HIP_MEMORY_SCOPE_AGENT);
            ull* dst = (ull*)(hsm + srow * LDH2 + sseg * 32);
            dst[0]=v0; dst[1]=v1; dst[2]=v2; dst[3]=v3;
            dst[4]=v4; dst[5]=v5; dst[6]=v6; dst[7]=v7;
        }
        __syncthreads();   // S1: h staged

        // ---- wave (nt,kh): 8 MFMAs over its K-half, dual accumulators ----
        {
            f32x4 accA = {0.f,0.f,0.f,0.f}, accB = {0.f,0.f,0.f,0.f};
            const unsigned short* ap = hsm + fr * LDH2 + kh * 256 + fk;
            const unsigned short* bp = wsm + (nt * 16 + fr) * LDW2 + kh * 256 + fk;
            #pragma unroll
            for (int ks = 0; ks < 8; ks += 2) {
                short8 a0 = *(const short8*)(ap + ks * 32);
                short8 b0 = *(const short8*)(bp + ks * 32);
                accA = __builtin_amdgcn_mfma_f32_16x16x32_bf16(a0, b0, accA, 0, 0, 0);
                short8 a1 = *(const short8*)(ap + ks * 32 + 32);
                short8 b1 = *(const short8*)(bp + ks * 32 + 32);
                accB = __builtin_amdgcn_mfma_f32_16x16x32_bf16(a1, b1, accB, 0, 0, 0);
            }
            #pragma unroll
            for (int e = 0; e < 4; ++e)
                gbufs[kh][(lane >> 4) * 4 + e][nt * 16 + fr] = accA[e] + accB[e];
        }
        __syncthreads();   // S2: gates complete

        // ---- cell update + DIRECT pair-packed publish (threads 0..127) ----
        if (tid < 128) {
            float4 g0 = *(const float4*)&gbufs[0][bl & 15][hj * 4];
            float4 g1 = *(const float4*)&gbufs[1][bl & 15][hj * 4];
            float ig = g0.x + g1.x + bf2f(xv.x) + bias4.x;
            float fg = g0.y + g1.y + bf2f(xv.y) + bias4.y;
            float gg = g0.z + g1.z + bf2f(xv.z) + bias4.z;
            float og = g0.w + g1.w + bf2f(xv.w) + bias4.w;
            ig = 1.f / (1.f + __expf(-ig));
            fg = 1.f / (1.f + __expf(-fg));
            og = 1.f / (1.f + __expf(-og));
            gg = tanhf(gg);
            creg = fg * creg + ig * gg;
            hout = og * tanhf(creg);

            if (t < TSTEPS - 1) {
                unsigned int hbits = f2bf(hout);
                unsigned int other = (unsigned int)__shfl_xor((int)hbits, 1, 64);
                if (!(hj & 1)) {
                    unsigned int packed = hbits | (other << 16);
                    unsigned int* dst = (unsigned int*)hn
                        + ((size_t)bglob * H + hcol) / 2;
                    __hip_atomic_store(dst, packed, __ATOMIC_RELAXED,
                                       __HIP_MEMORY_SCOPE_AGENT);
                }
            }
        }
        xv = xnext;

        // ---- arrive: drain own stores, then one flag store per block ----
        if (t < TSTEPS - 1) {
            asm volatile("s_waitcnt vmcnt(0)" ::: "memory");
            __syncthreads();   // S3: all publishes drained
            if (tid == 0)
                __hip_atomic_store(gflags + cg * 32, (unsigned int)(t + 1),
                                   __ATOMIC_RELAXED, __HIP_MEMORY_SCOPE_AGENT);
        }
    }

    if (tid < 128) {
        out[(size_t)bglob * H + hcol] = hout;                       // hy
        out[(size_t)B * H + (size_t)bglob * H + hcol] = creg;       // cy
    }
}

// ===========================================================================
// FALLBACK PATH (round-2 proven): per-step launches, K=1024
// ===========================================================================
#define KT  256
#define LDP 264

__global__ void init_state_fb(const float* __restrict__ hx,
                              const float* __restrict__ cx,
                              const float* __restrict__ bih,
                              const float* __restrict__ bhh,
                              unsigned short* __restrict__ hbf0,
                              float* __restrict__ cbuf,
                              float* __restrict__ bias2) {
    int i = blockIdx.x * 256 + threadIdx.x;
    if (i < B * H) { hbf0[i] = f2bf(hx[i]); cbuf[i] = cx[i]; }
    if (i < G) bias2[i] = bih[col2g_fb(i)] + bhh[col2g_fb(i)];
}

__global__ void pack_w(const float* __restrict__ wih,
                       const float* __restrict__ whh,
                       unsigned short* __restrict__ wbf) {
    int idx = blockIdx.x * 256 + threadIdx.x;
    int col = idx >> 8;
    int k0  = (idx & 255) << 2;
    int g = col2g_fb(col);
    float4 v = (k0 < I) ? *(const float4*)(wih + (size_t)g * I + k0)
                        : *(const float4*)(whh + (size_t)g * H + (k0 - I));
    ushort4 o = { f2bf(v.x), f2bf(v.y), f2bf(v.z), f2bf(v.w) };
    *(ushort4*)(wbf + (size_t)col * K + k0) = o;
}

__global__ __launch_bounds__(256) void lstm_step(
    const float* __restrict__ x_t,
    const unsigned short* __restrict__ wbf,
    const float* __restrict__ bias2,
    const unsigned short* __restrict__ h_prev,
    unsigned short* __restrict__ h_next,
    float* __restrict__ c)
{
    __shared__ unsigned short xs [32 * LDP];
    __shared__ unsigned short wsm2[32 * LDP];
    __shared__ float gbuf[32][33];

    const int tid  = threadIdx.x;
    const int mg   = blockIdx.x;
    const int nb   = blockIdx.y;
    const int lane = tid & 63;
    const int wv   = tid >> 6;
    const int rbase = mg * 32;
    const int cbase = nb * 32;
    const int fr = lane & 15;
    const int fk = (lane >> 4) * 8;
    const int sr = tid >> 3;
    const int sc = (tid & 7) * 8;

    f32x4 accA = {0.f,0.f,0.f,0.f}, accB = {0.f,0.f,0.f,0.f};

    for (int kt = 0; kt < K; kt += KT) {
        if (kt < I) {
            const float* src = x_t + (size_t)(rbase + sr) * I + kt;
            unsigned short* dst = xs + sr * LDP;
            #pragma unroll
            for (int j = 0; j < 4; ++j) {
                int k = sc + j * 64;
                float4 a = *(const float4*)(src + k);
                float4 b = *(const float4*)(src + k + 4);
                u16x8 o;
                o[0]=f2bf(a.x); o[1]=f2bf(a.y); o[2]=f2bf(a.z); o[3]=f2bf(a.w);
                o[4]=f2bf(b.x); o[5]=f2bf(b.y); o[6]=f2bf(b.z); o[7]=f2bf(b.w);
                *(u16x8*)(dst + k) = o;
            }
        } else {
            const unsigned short* src = h_prev + (size_t)(rbase + sr) * H + (kt - I);
            unsigned short* dst = xs + sr * LDP;
            #pragma unroll
            for (int j = 0; j < 4; ++j) {
                int k = sc + j * 64;
                *(u16x8*)(dst + k) = *(const u16x8*)(src + k);
            }
        }
        {
            const unsigned short* src = wbf + (size_t)(cbase + sr) * K + kt;
            unsigned short* dst = wsm2 + sr * LDP;
            #pragma unroll
            for (int j = 0; j < 4; ++j) {
                int k = sc + j * 64;
                *(u16x8*)(dst + k) = *(const u16x8*)(src + k);
            }
        }
        __syncthreads();
        const unsigned short* ap = xs   + ((wv & 1) * 16 + fr) * LDP + fk;
        const unsigned short* bp = wsm2 + ((wv >> 1) * 16 + fr) * LDP + fk;
        #pragma unroll
        for (int ks = 0; ks < KT / 32; ++ks) {
            short8 af = *(const short8*)(ap + ks * 32);
            short8 bf = *(const short8*)(bp + ks * 32);
            if (ks & 1) accB = __builtin_amdgcn_mfma_f32_16x16x32_bf16(af, bf, accB, 0, 0, 0);
            else        accA = __builtin_amdgcn_mfma_f32_16x16x32_bf16(af, bf, accA, 0, 0, 0);
        }
        __syncthreads();
    }

    #pragma unroll
    for (int e = 0; e < 4; ++e)
        gbuf[(wv & 1) * 16 + (lane >> 4) * 4 + e][(wv >> 1) * 16 + fr] = accA[e] + accB[e];
    __syncthreads();

    {
        int br = tid >> 3;
        int hj = tid & 7;
        float ig = gbuf[br][ 0 + hj] + bias2[cbase +  0 + hj];
        float fg = gbuf[br][ 8 + hj] + bias2[cbase +  8 + hj];
        float gg = gbuf[br][16 + hj] + bias2[cbase + 16 + hj];
        float og = gbuf[br][24 + hj] + bias2[cbase + 24 + hj];
        ig = 1.f / (1.f + __expf(-ig));
        fg = 1.f / (1.f + __expf(-fg));
        og = 1.f / (1.f + __expf(-og));
        gg = tanhf(gg);
        size_t ci = (size_t)(rbase + br) * H + nb * 8 + hj;
        float cn = fg * c[ci] + ig * gg;
        c[ci] = cn;
        h_next[ci] = f2bf(og * tanhf(cn));
    }
}

__global__ void epilogue(const unsigned short* __restrict__ hbf,
                         const float* __restrict__ cfin,
                         float* __restrict__ out) {
    int i = blockIdx.x * 256 + threadIdx.x;
    if (i < B * H) {
        out[i] = bf2f(hbf[i]);
        out[B * H + i] = cfin[i];
    }
}

// ===========================================================================
extern "C" void kernel_launch(void* const* d_in, const int* in_sizes, int n_in,
                              void* d_out, int out_size, void* d_ws, size_t ws_size,
                              hipStream_t stream) {
    const float* input = (const float*)d_in[0];
    const float* hx    = (const float*)d_in[1];
    const float* cx    = (const float*)d_in[2];
    const float* wih   = (const float*)d_in[3];
    const float* whh   = (const float*)d_in[4];
    const float* bih   = (const float*)d_in[5];
    const float* bhh   = (const float*)d_in[6];
    float* out = (float*)d_out;
    char* ws = (char*)d_ws;

    const size_t PERSIST_WS = 172138496ULL;

    if (ws_size >= PERSIST_WS) {
        unsigned short* xpBuf = (unsigned short*)(ws);                 // 128 MB
        unsigned short* xbf   = (unsigned short*)(ws + 134217728);     // 32 MB
        unsigned short* wihP  = (unsigned short*)(ws + 167772160);     // 2 MB
        unsigned short* whhP  = (unsigned short*)(ws + 169869312);     // 2 MB
        float*          bias2 = (float*)         (ws + 171966464);     // 8 KB
        unsigned short* hb0   = (unsigned short*)(ws + 171974656);     // 64 KB
        unsigned short* hb1   = (unsigned short*)(ws + 172040192);     // 64 KB
        unsigned int*   flags = (unsigned int*)  (ws + 172105728);     // 32 KB

        hipMemsetAsync(flags, 0, 32768, stream);
        conv_x<<<(TSTEPS * B * I) / (256 * 8), 256, 0, stream>>>(input, xbf);
        pack_w2<<<(G * 128) / 256, 256, 0, stream>>>(wih, whh, wihP, whhP);
        init_state_p<<<B * H / 256, 256, 0, stream>>>(hx, bih, bhh, hb0, bias2);
        dim3 ggrid(TSTEPS, G / 128);
        xproj_gemm<<<ggrid, 256, 0, stream>>>(xbf, wihP, xpBuf);
        dim3 pgrid(64, 4);
        lstm_persist_v2<<<pgrid, 256, 0, stream>>>(xpBuf, whhP, bias2, cx,
                                                   hb0, hb1, out, flags);
    } else {
        unsigned short* wbf   = (unsigned short*)(ws);
        float*          bias2 = (float*)(ws + 4194304);
        float*          cbuf  = (float*)(ws + 4194304 + 8192);
        unsigned short* hbf0  = (unsigned short*)(ws + 4333568);
        unsigned short* hbf1  = (unsigned short*)(ws + 4399104);

        pack_w<<<G * K / 4 / 256, 256, 0, stream>>>(wih, whh, wbf);
        init_state_fb<<<B * H / 256, 256, 0, stream>>>(hx, cx, bih, bhh, hbf0, cbuf, bias2);
        dim3 grid(2, 64);
        for (int t = 0; t < TSTEPS; ++t) {
            lstm_step<<<grid, 256, 0, stream>>>(
                input + (size_t)t * B * I, wbf, bias2,
                (t & 1) ? hbf1 : hbf0,
                (t & 1) ? hbf0 : hbf1,
                cbuf);
        }
        epilogue<<<B * H / 256, 256, 0, stream>>>(hbf0, cbuf, out);
    }
}

// Round 14
// 1706.807 us; speedup vs baseline: 4.2091x; 1.0522x over previous
//
#include <hip/hip_runtime.h>
#include <math.h>

#define TSTEPS 512
#define B      64
#define I      512
#define H      512
#define G      2048   // 4*H
#define K      1024   // I + H

typedef __attribute__((ext_vector_type(8))) short          short8;  // MFMA frag
typedef __attribute__((ext_vector_type(8))) unsigned short u16x8;
typedef __attribute__((ext_vector_type(4))) float          f32x4;
typedef unsigned long long ull;

__device__ __forceinline__ unsigned short f2bf(float f) {
    union { float f; unsigned int u; } v; v.f = f;
    unsigned int r = v.u + 0x7fffu + ((v.u >> 16) & 1u);   // RNE
    return (unsigned short)(r >> 16);
}
__device__ __forceinline__ float bf2f(unsigned short b) {
    union { unsigned int u; float f; } v; v.u = ((unsigned int)b) << 16;
    return v.f;
}

// persist packing: col = cg*32 + hj*4 + gate  (gate fastest)
//   <-> g = gate*H + cg*8 + hj    (cg = col>>5)
__device__ __forceinline__ int col2g3(int col) {
    int w = col & 31, cg = col >> 5;
    return (w & 3) * H + cg * 8 + (w >> 2);
}
// fallback packing (round-2 proven)
__device__ __forceinline__ int col2g_fb(int col) {
    int w = col & 31, nb = col >> 5;
    return (w >> 3) * H + nb * 8 + (w & 7);
}

// ===========================================================================
// PERSISTENT PATH  (exact R6 configuration — measured optimum: 1709 us total)
// ===========================================================================

__global__ void conv_x(const float* __restrict__ in, unsigned short* __restrict__ xbf) {
    int i = blockIdx.x * 256 + threadIdx.x;
    size_t base = (size_t)i * 8;
    float4 a = *(const float4*)(in + base);
    float4 b = *(const float4*)(in + base + 4);
    u16x8 o;
    o[0]=f2bf(a.x); o[1]=f2bf(a.y); o[2]=f2bf(a.z); o[3]=f2bf(a.w);
    o[4]=f2bf(b.x); o[5]=f2bf(b.y); o[6]=f2bf(b.z); o[7]=f2bf(b.w);
    *(u16x8*)(xbf + base) = o;
}

__global__ void pack_w2(const float* __restrict__ wih,
                        const float* __restrict__ whh,
                        unsigned short* __restrict__ wihP,
                        unsigned short* __restrict__ whhP) {
    int idx = blockIdx.x * 256 + threadIdx.x;   // [0, G*128)
    int col = idx >> 7;
    int k0  = (idx & 127) << 2;
    int g = col2g3(col);
    float4 a = *(const float4*)(wih + (size_t)g * I + k0);
    float4 b = *(const float4*)(whh + (size_t)g * H + k0);
    ushort4 oa = { f2bf(a.x), f2bf(a.y), f2bf(a.z), f2bf(a.w) };
    ushort4 ob = { f2bf(b.x), f2bf(b.y), f2bf(b.z), f2bf(b.w) };
    *(ushort4*)(wihP + (size_t)col * I + k0) = oa;
    *(ushort4*)(whhP + (size_t)col * H + k0) = ob;
}

__global__ void init_state_p(const float* __restrict__ hx,
                             const float* __restrict__ bih,
                             const float* __restrict__ bhh,
                             unsigned short* __restrict__ hbf0,
                             float* __restrict__ bias2) {
    int i = blockIdx.x * 256 + threadIdx.x;
    if (i < B * H) hbf0[i] = f2bf(hx[i]);
    if (i < G) bias2[i] = bih[col2g3(i)] + bhh[col2g3(i)];
}

// xp[cg][t][b][32] bf16.  grid (512 t, 16 ncb), 256 thr.
#define LDA 136
#define LDB 136
__global__ __launch_bounds__(256) void xproj_gemm(
    const unsigned short* __restrict__ xbf,   // [T*B][I]
    const unsigned short* __restrict__ wihP,  // [G][I] packed col2g3
    unsigned short* __restrict__ xp)          // [64][512][64][32]
{
    __shared__ unsigned short atile[64 * LDA];
    __shared__ unsigned short btile[128 * LDB];

    const int t   = blockIdx.x;
    const int ncb = blockIdx.y;
    const int tid  = threadIdx.x;
    const int lane = tid & 63;
    const int wv   = tid >> 6;
    const int fr   = lane & 15;
    const int fk   = (lane >> 4) * 8;
    const int mt   = wv & 1;
    const int nt   = wv >> 1;

    f32x4 acc[2][4];
    #pragma unroll
    for (int mi = 0; mi < 2; ++mi)
        #pragma unroll
        for (int ni = 0; ni < 4; ++ni) acc[mi][ni] = (f32x4){0.f,0.f,0.f,0.f};

    const int arow = tid >> 2, aseg = tid & 3;
    const int brow = tid >> 1, bseg = tid & 1;

    for (int kt = 0; kt < I; kt += 128) {
        {
            const u16x8* src = (const u16x8*)(xbf + ((size_t)t * 64 + arow) * I + kt);
            #pragma unroll
            for (int j = 0; j < 4; ++j) {
                int ch = aseg + 4 * j;
                *(u16x8*)(atile + arow * LDA + ch * 8) = src[ch];
            }
        }
        {
            const u16x8* src = (const u16x8*)(wihP + ((size_t)ncb * 128 + brow) * I + kt);
            #pragma unroll
            for (int j = 0; j < 8; ++j) {
                int ch = bseg + 2 * j;
                *(u16x8*)(btile + brow * LDB + ch * 8) = src[ch];
            }
        }
        __syncthreads();
        #pragma unroll
        for (int ks = 0; ks < 4; ++ks) {
            short8 af[2], bf[4];
            #pragma unroll
            for (int mi = 0; mi < 2; ++mi)
                af[mi] = *(const short8*)(atile + (mt*32 + mi*16 + fr) * LDA + fk + ks*32);
            #pragma unroll
            for (int ni = 0; ni < 4; ++ni)
                bf[ni] = *(const short8*)(btile + (nt*64 + ni*16 + fr) * LDB + fk + ks*32);
            #pragma unroll
            for (int mi = 0; mi < 2; ++mi)
                #pragma unroll
                for (int ni = 0; ni < 4; ++ni)
                    acc[mi][ni] = __builtin_amdgcn_mfma_f32_16x16x32_bf16(af[mi], bf[ni], acc[mi][ni], 0, 0, 0);
        }
        __syncthreads();
    }

    #pragma unroll
    for (int mi = 0; mi < 2; ++mi)
        #pragma unroll
        for (int ni = 0; ni < 4; ++ni)
            #pragma unroll
            for (int e = 0; e < 4; ++e) {
                int row = mt*32 + mi*16 + (lane >> 4) * 4 + e;       // batch b
                int c   = ncb*128 + nt*64 + ni*16 + fr;              // packed col
                int cgv = c >> 5, coff = c & 31;
                xp[(((size_t)cgv * TSTEPS + t) * 64 + row) * 32 + coff] = f2bf(acc[mi][ni][e]);
            }
}

// ---------------------------------------------------------------------------
// Persistent LSTM: grid (64 cg, 4 bg) = 256 blocks x 256 thr (4 waves).
// Block (cg,bg): gates[16 rows][32 pcols], whh slice (32KB) LDS-resident,
// h slice 16x512 staged per step via sc1 loads (split-K overlap), c in regs.
// Sync: per-bg group of 64 blocks, flag-per-block stores + wave-wide poll.
// ---------------------------------------------------------------------------
#define LDH2 520
#define LDW2 520
__global__ __launch_bounds__(256) void lstm_persist256(
    const unsigned short* __restrict__ xp,     // [64][512][64][32]
    const unsigned short* __restrict__ whhP,   // [G][H] packed col2g3
    const float* __restrict__ bias2,           // [G] packed
    const float* __restrict__ cx,              // [B][H]
    unsigned short* __restrict__ hb0,          // [B][H] bf16 (h init)
    unsigned short* __restrict__ hb1,
    float* __restrict__ out,                   // [2][B][H]
    unsigned int* __restrict__ flags)          // [4][64][32] u32, zeroed
{
    __shared__ unsigned short hsm[16 * LDH2];   // 16.6 KB
    __shared__ unsigned short wsm[32 * LDW2];   // 33.3 KB
    __shared__ float gbuf[16][36];              //  2.3 KB
    __shared__ unsigned short hsmall[16][8];    //  256 B

    const int tid  = threadIdx.x;
    const int cg   = blockIdx.x;               // [0,64)
    const int bg   = blockIdx.y;               // [0,4)
    const int lane = tid & 63;
    const int wv   = tid >> 6;                 // [0,4)
    const int fr   = lane & 15;
    const int fk   = (lane >> 4) * 8;
    const int nt   = wv & 1;                   // N-tile (16 cols)
    const int kh   = wv >> 1;                  // K-half

    // ---- stage whh slice once: 32 packed cols x 512 k ----
    {
        int row = tid >> 3, seg = tid & 7;
        const u16x8* src = (const u16x8*)(whhP + ((size_t)cg * 32 + row) * H + seg * 64);
        unsigned short* dst = wsm + row * LDW2 + seg * 64;
        #pragma unroll
        for (int j = 0; j < 8; ++j) *(u16x8*)(dst + j * 8) = src[j];
    }

    // ---- per-thread cell state (threads 0..127) ----
    const int bl   = tid >> 3;                 // local batch row (valid tid<128)
    const int hj   = tid & 7;
    const int hcol = cg * 8 + hj;
    const int bglob = bg * 16 + (bl & 15);
    float creg = 0.f;
    float4 bias4 = {0.f, 0.f, 0.f, 0.f};
    if (tid < 128) {
        creg  = cx[(size_t)bglob * H + hcol];
        bias4 = *(const float4*)&bias2[cg * 32 + hj * 4];
    }

    // h staging map: 16 thr/row, 16 shorts (4 ull) per half per thread
    const int srow = tid >> 4, sseg = tid & 15;

    const unsigned short* xpb =
        xp + (((size_t)cg * TSTEPS) * 64 + bg * 16 + (bl & 15)) * 32 + hj * 4;
    ushort4 xv = {0, 0, 0, 0};
    if (tid < 128) xv = *(const ushort4*)xpb;

    unsigned int* gflags = flags + (size_t)bg * 64 * 32;   // this group's flags
    float hout = 0.f;

    for (int t = 0; t < TSTEPS; ++t) {
        const unsigned short* hp = (t & 1) ? hb1 : hb0;
        unsigned short*       hn = (t & 1) ? hb0 : hb1;

        // ---- wait for all 64 group members to have published h(t) ----
        if (t > 0) {
            if (wv == 0) {
                const unsigned int* fp = gflags + lane * 32;
                unsigned int tgt = (unsigned int)t;
                while (true) {
                    unsigned int v = __hip_atomic_load(fp, __ATOMIC_RELAXED,
                                                       __HIP_MEMORY_SCOPE_AGENT);
                    if (__ballot(v < tgt) == 0ull) break;
                }
            }
            __syncthreads();
        }

        // ---- issue all h loads (sc1, bypass stale L2): 4 ull per half ----
        const ull* gp  = (const ull*)(hp + ((size_t)bg * 16 + srow) * H + sseg * 16);
        ull a0 = __hip_atomic_load(gp + 0,  __ATOMIC_RELAXED, __HIP_MEMORY_SCOPE_AGENT);
        ull a1 = __hip_atomic_load(gp + 1,  __ATOMIC_RELAXED, __HIP_MEMORY_SCOPE_AGENT);
        ull a2 = __hip_atomic_load(gp + 2,  __ATOMIC_RELAXED, __HIP_MEMORY_SCOPE_AGENT);
        ull a3 = __hip_atomic_load(gp + 3,  __ATOMIC_RELAXED, __HIP_MEMORY_SCOPE_AGENT);
        const ull* gp1 = (const ull*)(hp + ((size_t)bg * 16 + srow) * H + 256 + sseg * 16);
        ull b0 = __hip_atomic_load(gp1 + 0, __ATOMIC_RELAXED, __HIP_MEMORY_SCOPE_AGENT);
        ull b1 = __hip_atomic_load(gp1 + 1, __ATOMIC_RELAXED, __HIP_MEMORY_SCOPE_AGENT);
        ull b2 = __hip_atomic_load(gp1 + 2, __ATOMIC_RELAXED, __HIP_MEMORY_SCOPE_AGENT);
        ull b3 = __hip_atomic_load(gp1 + 3, __ATOMIC_RELAXED, __HIP_MEMORY_SCOPE_AGENT);
        ushort4 xnext = xv;
        if (tid < 128 && t + 1 < TSTEPS)
            xnext = *(const ushort4*)(xpb + (size_t)(t + 1) * 64 * 32);

        // ---- stage K-half 0 (compiler waits only on a0..a3) ----
        {
            ull* d0 = (ull*)(hsm + srow * LDH2 + sseg * 16);
            d0[0] = a0; d0[1] = a1; d0[2] = a2; d0[3] = a3;
        }
        __syncthreads();   // S1: half0 staged

        // ---- kh=0 waves: MFMA on k in [0,256) while half1 drains ----
        f32x4 acc = {0.f, 0.f, 0.f, 0.f};
        if (kh == 0) {
            const unsigned short* ap = hsm + fr * LDH2 + fk;
            const unsigned short* bp = wsm + (nt * 16 + fr) * LDW2 + fk;
            #pragma unroll
            for (int ks = 0; ks < 8; ++ks) {
                short8 af = *(const short8*)(ap + ks * 32);
                short8 bf = *(const short8*)(bp + ks * 32);
                acc = __builtin_amdgcn_mfma_f32_16x16x32_bf16(af, bf, acc, 0, 0, 0);
            }
            #pragma unroll
            for (int e = 0; e < 4; ++e)
                gbuf[(lane >> 4) * 4 + e][nt * 16 + fr] = acc[e];
        }

        // ---- stage K-half 1 ----
        {
            ull* d1 = (ull*)(hsm + srow * LDH2 + 256 + sseg * 16);
            d1[0] = b0; d1[1] = b1; d1[2] = b2; d1[3] = b3;
        }
        __syncthreads();   // S2: half1 staged (+ gbuf init from kh0)

        // ---- kh=1 waves: MFMA on k in [256,512), accumulate into gbuf ----
        if (kh == 1) {
            const unsigned short* ap = hsm + fr * LDH2 + 256 + fk;
            const unsigned short* bp = wsm + (nt * 16 + fr) * LDW2 + 256 + fk;
            #pragma unroll
            for (int ks = 0; ks < 8; ++ks) {
                short8 af = *(const short8*)(ap + ks * 32);
                short8 bf = *(const short8*)(bp + ks * 32);
                acc = __builtin_amdgcn_mfma_f32_16x16x32_bf16(af, bf, acc, 0, 0, 0);
            }
            #pragma unroll
            for (int e = 0; e < 4; ++e)
                gbuf[(lane >> 4) * 4 + e][nt * 16 + fr] += acc[e];
        }
        __syncthreads();   // S3: gates complete

        // ---- cell update (threads 0..127) ----
        if (tid < 128) {
            float4 g4 = *(const float4*)&gbuf[bl & 15][hj * 4];
            float ig = g4.x + bf2f(xv.x) + bias4.x;
            float fg = g4.y + bf2f(xv.y) + bias4.y;
            float gg = g4.z + bf2f(xv.z) + bias4.z;
            float og = g4.w + bf2f(xv.w) + bias4.w;
            ig = 1.f / (1.f + __expf(-ig));
            fg = 1.f / (1.f + __expf(-fg));
            og = 1.f / (1.f + __expf(-og));
            gg = tanhf(gg);
            creg = fg * creg + ig * gg;
            hout = og * tanhf(creg);
            hsmall[bl & 15][hj] = f2bf(hout);
        }
        xv = xnext;

        // ---- publish h slice + flag (wave 0 only) ----
        if (t < TSTEPS - 1) {
            __syncthreads();   // S4: hsmall ready
            if (wv == 0) {
                if (lane < 32) {
                    int r = lane >> 1, half = lane & 1;
                    ull hv = *(const ull*)&hsmall[r][half * 4];
                    ull* dstp = (ull*)(hn + ((size_t)bg * 16 + r) * H + cg * 8 + half * 4);
                    __hip_atomic_store(dstp, hv, __ATOMIC_RELAXED, __HIP_MEMORY_SCOPE_AGENT);
                }
                asm volatile("s_waitcnt vmcnt(0)" ::: "memory");
                if (lane == 0)
                    __hip_atomic_store(gflags + cg * 32, (unsigned int)(t + 1),
                                       __ATOMIC_RELAXED, __HIP_MEMORY_SCOPE_AGENT);
            }
        }
    }

    if (tid < 128) {
        out[(size_t)bglob * H + hcol] = hout;                       // hy
        out[(size_t)B * H + (size_t)bglob * H + hcol] = creg;       // cy
    }
}

// ===========================================================================
// FALLBACK PATH (round-2 proven): per-step launches, K=1024
// ===========================================================================
#define KT  256
#define LDP 264

__global__ void init_state_fb(const float* __restrict__ hx,
                              const float* __restrict__ cx,
                              const float* __restrict__ bih,
                              const float* __restrict__ bhh,
                              unsigned short* __restrict__ hbf0,
                              float* __restrict__ cbuf,
                              float* __restrict__ bias2) {
    int i = blockIdx.x * 256 + threadIdx.x;
    if (i < B * H) { hbf0[i] = f2bf(hx[i]); cbuf[i] = cx[i]; }
    if (i < G) bias2[i] = bih[col2g_fb(i)] + bhh[col2g_fb(i)];
}

__global__ void pack_w(const float* __restrict__ wih,
                       const float* __restrict__ whh,
                       unsigned short* __restrict__ wbf) {
    int idx = blockIdx.x * 256 + threadIdx.x;
    int col = idx >> 8;
    int k0  = (idx & 255) << 2;
    int g = col2g_fb(col);
    float4 v = (k0 < I) ? *(const float4*)(wih + (size_t)g * I + k0)
                        : *(const float4*)(whh + (size_t)g * H + (k0 - I));
    ushort4 o = { f2bf(v.x), f2bf(v.y), f2bf(v.z), f2bf(v.w) };
    *(ushort4*)(wbf + (size_t)col * K + k0) = o;
}

__global__ __launch_bounds__(256) void lstm_step(
    const float* __restrict__ x_t,
    const unsigned short* __restrict__ wbf,
    const float* __restrict__ bias2,
    const unsigned short* __restrict__ h_prev,
    unsigned short* __restrict__ h_next,
    float* __restrict__ c)
{
    __shared__ unsigned short xs [32 * LDP];
    __shared__ unsigned short wsm2[32 * LDP];
    __shared__ float gbuf[32][33];

    const int tid  = threadIdx.x;
    const int mg   = blockIdx.x;
    const int nb   = blockIdx.y;
    const int lane = tid & 63;
    const int wv   = tid >> 6;
    const int rbase = mg * 32;
    const int cbase = nb * 32;
    const int fr = lane & 15;
    const int fk = (lane >> 4) * 8;
    const int sr = tid >> 3;
    const int sc = (tid & 7) * 8;

    f32x4 accA = {0.f,0.f,0.f,0.f}, accB = {0.f,0.f,0.f,0.f};

    for (int kt = 0; kt < K; kt += KT) {
        if (kt < I) {
            const float* src = x_t + (size_t)(rbase + sr) * I + kt;
            unsigned short* dst = xs + sr * LDP;
            #pragma unroll
            for (int j = 0; j < 4; ++j) {
                int k = sc + j * 64;
                float4 a = *(const float4*)(src + k);
                float4 b = *(const float4*)(src + k + 4);
                u16x8 o;
                o[0]=f2bf(a.x); o[1]=f2bf(a.y); o[2]=f2bf(a.z); o[3]=f2bf(a.w);
                o[4]=f2bf(b.x); o[5]=f2bf(b.y); o[6]=f2bf(b.z); o[7]=f2bf(b.w);
                *(u16x8*)(dst + k) = o;
            }
        } else {
            const unsigned short* src = h_prev + (size_t)(rbase + sr) * H + (kt - I);
            unsigned short* dst = xs + sr * LDP;
            #pragma unroll
            for (int j = 0; j < 4; ++j) {
                int k = sc + j * 64;
                *(u16x8*)(dst + k) = *(const u16x8*)(src + k);
            }
        }
        {
            const unsigned short* src = wbf + (size_t)(cbase + sr) * K + kt;
            unsigned short* dst = wsm2 + sr * LDP;
            #pragma unroll
            for (int j = 0; j < 4; ++j) {
                int k = sc + j * 64;
                *(u16x8*)(dst + k) = *(const u16x8*)(src + k);
            }
        }
        __syncthreads();
        const unsigned short* ap = xs   + ((wv & 1) * 16 + fr) * LDP + fk;
        const unsigned short* bp = wsm2 + ((wv >> 1) * 16 + fr) * LDP + fk;
        #pragma unroll
        for (int ks = 0; ks < KT / 32; ++ks) {
            short8 af = *(const short8*)(ap + ks * 32);
            short8 bf = *(const short8*)(bp + ks * 32);
            if (ks & 1) accB = __builtin_amdgcn_mfma_f32_16x16x32_bf16(af, bf, accB, 0, 0, 0);
            else        accA = __builtin_amdgcn_mfma_f32_16x16x32_bf16(af, bf, accA, 0, 0, 0);
        }
        __syncthreads();
    }

    #pragma unroll
    for (int e = 0; e < 4; ++e)
        gbuf[(wv & 1) * 16 + (lane >> 4) * 4 + e][(wv >> 1) * 16 + fr] = accA[e] + accB[e];
    __syncthreads();

    {
        int br = tid >> 3;
        int hj = tid & 7;
        float ig = gbuf[br][ 0 + hj] + bias2[cbase +  0 + hj];
        float fg = gbuf[br][ 8 + hj] + bias2[cbase +  8 + hj];
        float gg = gbuf[br][16 + hj] + bias2[cbase + 16 + hj];
        float og = gbuf[br][24 + hj] + bias2[cbase + 24 + hj];
        ig = 1.f / (1.f + __expf(-ig));
        fg = 1.f / (1.f + __expf(-fg));
        og = 1.f / (1.f + __expf(-og));
        gg = tanhf(gg);
        size_t ci = (size_t)(rbase + br) * H + nb * 8 + hj;
        float cn = fg * c[ci] + ig * gg;
        c[ci] = cn;
        h_next[ci] = f2bf(og * tanhf(cn));
    }
}

__global__ void epilogue(const unsigned short* __restrict__ hbf,
                         const float* __restrict__ cfin,
                         float* __restrict__ out) {
    int i = blockIdx.x * 256 + threadIdx.x;
    if (i < B * H) {
        out[i] = bf2f(hbf[i]);
        out[B * H + i] = cfin[i];
    }
}

// ===========================================================================
extern "C" void kernel_launch(void* const* d_in, const int* in_sizes, int n_in,
                              void* d_out, int out_size, void* d_ws, size_t ws_size,
                              hipStream_t stream) {
    const float* input = (const float*)d_in[0];
    const float* hx    = (const float*)d_in[1];
    const float* cx    = (const float*)d_in[2];
    const float* wih   = (const float*)d_in[3];
    const float* whh   = (const float*)d_in[4];
    const float* bih   = (const float*)d_in[5];
    const float* bhh   = (const float*)d_in[6];
    float* out = (float*)d_out;
    char* ws = (char*)d_ws;

    const size_t PERSIST_WS = 172236864ULL;

    if (ws_size >= PERSIST_WS) {
        unsigned short* xpBuf = (unsigned short*)(ws);                 // 128 MB
        unsigned short* xbf   = (unsigned short*)(ws + 134217728);     // 32 MB
        unsigned short* wihP  = (unsigned short*)(ws + 167772160);     // 2 MB
        unsigned short* whhP  = (unsigned short*)(ws + 169869312);     // 2 MB
        float*          bias2 = (float*)         (ws + 171966464);     // 8 KB
        unsigned short* hb0   = (unsigned short*)(ws + 171974656);     // 64 KB
        unsigned short* hb1   = (unsigned short*)(ws + 172040192);     // 64 KB
        unsigned int*   flags = (unsigned int*)  (ws + 172105728);     // 32 KB

        hipMemsetAsync(flags, 0, 32768, stream);
        conv_x<<<(TSTEPS * B * I) / (256 * 8), 256, 0, stream>>>(input, xbf);
        pack_w2<<<(G * 128) / 256, 256, 0, stream>>>(wih, whh, wihP, whhP);
        init_state_p<<<B * H / 256, 256, 0, stream>>>(hx, bih, bhh, hb0, bias2);
        dim3 ggrid(TSTEPS, G / 128);
        xproj_gemm<<<ggrid, 256, 0, stream>>>(xbf, wihP, xpBuf);
        dim3 pgrid(64, 4);
        lstm_persist256<<<pgrid, 256, 0, stream>>>(xpBuf, whhP, bias2, cx,
                                                   hb0, hb1, out, flags);
    } else {
        unsigned short* wbf   = (unsigned short*)(ws);
        float*          bias2 = (float*)(ws + 4194304);
        float*          cbuf  = (float*)(ws + 4194304 + 8192);
        unsigned short* hbf0  = (unsigned short*)(ws + 4333568);
        unsigned short* hbf1  = (unsigned short*)(ws + 4399104);

        pack_w<<<G * K / 4 / 256, 256, 0, stream>>>(wih, whh, wbf);
        init_state_fb<<<B * H / 256, 256, 0, stream>>>(hx, cx, bih, bhh, hbf0, cbuf, bias2);
        dim3 grid(2, 64);
        for (int t = 0; t < TSTEPS; ++t) {
            lstm_step<<<grid, 256, 0, stream>>>(
                input + (size_t)t * B * I, wbf, bias2,
                (t & 1) ? hbf1 : hbf0,
                (t & 1) ? hbf0 : hbf1,
                cbuf);
        }
        epilogue<<<B * H / 256, 256, 0, stream>>>(hbf0, cbuf, out);
    }
}